// Round 1
// baseline (407.368 us; speedup 1.0000x reference)
//
#include <hip/hip_runtime.h>
#include <cstdint>
#include <cstddef>

#define M_DIM 4096
#define N_DIM 8192
#define K_DIM 4096

typedef __attribute__((ext_vector_type(4))) int int4v;

// ---------------------------------------------------------------------------
// Pack: int32 (values 0..126) -> int8, A into pa [M,K], B into pb [N,K].
// Each thread converts 16 ints (4x dwordx4 loads) -> one 16B store.
// ---------------------------------------------------------------------------
__global__ void __launch_bounds__(256) pack_kernel(const int* __restrict__ a,
                                                   const int* __restrict__ b,
                                                   unsigned char* __restrict__ pa,
                                                   unsigned char* __restrict__ pb) {
    size_t t = (size_t)blockIdx.x * 256 + threadIdx.x;
    const size_t NA16 = (size_t)M_DIM * K_DIM / 16;  // A chunks
    const int* __restrict__ src;
    unsigned char* __restrict__ dst;
    if (t < NA16) {
        src = a; dst = pa;
    } else {
        src = b; dst = pb; t -= NA16;
    }
    const int4v* s4 = (const int4v*)src + t * 4;
    int4v o;
#pragma unroll
    for (int q = 0; q < 4; ++q) {
        int4v v = s4[q];
        o[q] = (v[0] & 0xff) | ((v[1] & 0xff) << 8) | ((v[2] & 0xff) << 16) | (v[3] << 24);
    }
    ((int4v*)dst)[t] = o;
}

// ---------------------------------------------------------------------------
// GEMM: C[m][n] = sum_k A[m][k]*B[n][k], int8 inputs, i32 accum,
// epilogue: * alpha_row[m] * alpha_col[n] -> fp16.
// m97 structure: 128x128 tile, 256 thr (2x2 waves, 64x64 each),
// BK=64 bytes, global_load_lds width=16 staging, mfma_i32_16x16x64_i8.
// ---------------------------------------------------------------------------
__device__ inline void async_copy16(const unsigned char* g, unsigned char* l) {
    __builtin_amdgcn_global_load_lds(
        (const __attribute__((address_space(1))) void*)g,
        (__attribute__((address_space(3))) void*)l,
        16, 0, 0);
}

__global__ void __launch_bounds__(256) gemm_i8(const unsigned char* __restrict__ Ap,
                                               const unsigned char* __restrict__ Bp,
                                               const _Float16* __restrict__ arow,
                                               const _Float16* __restrict__ acol,
                                               _Float16* __restrict__ Cout) {
    __shared__ __align__(16) unsigned char As[128 * 64];
    __shared__ __align__(16) unsigned char Bs[128 * 64];

    const int tid  = threadIdx.x;
    const int lane = tid & 63;
    const int wave = tid >> 6;
    const int bn   = blockIdx.x;  // 0..63
    const int bm   = blockIdx.y;  // 0..31

    const int wm = (wave & 1) * 64;   // wave's row offset within 128-tile
    const int wn = (wave >> 1) * 64;  // wave's col offset within 128-tile

    // --- staging addressing: wave w stages rows [w*32, w*32+32) of each tile,
    // in two 1KB chunks (16 rows each). lane covers row +lane>>2, bytes (lane&3)*16.
    const size_t a_row0 = (size_t)bm * 128;
    const size_t b_row0 = (size_t)bn * 128;
    const int stg_row = wave * 32 + (lane >> 2);
    const int stg_col = (lane & 3) * 16;

    const unsigned char* ag = Ap + (a_row0 + stg_row) * (size_t)K_DIM + stg_col;
    const unsigned char* bg = Bp + (b_row0 + stg_row) * (size_t)K_DIM + stg_col;
    unsigned char* al = As + wave * 2048;  // wave-uniform LDS base; HW adds lane*16
    unsigned char* bl = Bs + wave * 2048;

    // --- fragment addressing (16x16x64 i8: per-lane 16B at row=lane&15,
    // k-bytes (lane>>4)*16 — same byte layout as verified 16x16x32 bf16)
    const int fr_off   = (lane >> 4) * 16;
    const int a_fr_row = wm + (lane & 15);
    const int b_fr_row = wn + (lane & 15);

    int4v acc[4][4];
#pragma unroll
    for (int i = 0; i < 4; ++i)
#pragma unroll
        for (int j = 0; j < 4; ++j) acc[i][j] = (int4v)0;

    for (int kt = 0; kt < K_DIM; kt += 64) {
        async_copy16(ag + kt,                al);
        async_copy16(ag + kt + 16 * K_DIM,   al + 1024);
        async_copy16(bg + kt,                bl);
        async_copy16(bg + kt + 16 * K_DIM,   bl + 1024);
        __syncthreads();  // compiler emits vmcnt(0) drain before s_barrier

        int4v af[4], bf[4];
#pragma unroll
        for (int i = 0; i < 4; ++i)
            af[i] = *(const int4v*)(As + (a_fr_row + i * 16) * 64 + fr_off);
#pragma unroll
        for (int j = 0; j < 4; ++j)
            bf[j] = *(const int4v*)(Bs + (b_fr_row + j * 16) * 64 + fr_off);

#pragma unroll
        for (int i = 0; i < 4; ++i)
#pragma unroll
            for (int j = 0; j < 4; ++j)
                acc[i][j] = __builtin_amdgcn_mfma_i32_16x16x64_i8(af[i], bf[j],
                                                                  acc[i][j], 0, 0, 0);

        __syncthreads();
    }

    // --- epilogue: C/D layout col=lane&15, row=(lane>>4)*4+reg
    const int gcol0 = (int)b_row0 + wn + (lane & 15);
    float ac4[4];
#pragma unroll
    for (int j = 0; j < 4; ++j) ac4[j] = (float)acol[gcol0 + j * 16];

    const size_t grow0 = a_row0 + wm + (lane >> 4) * 4;
#pragma unroll
    for (int i = 0; i < 4; ++i) {
#pragma unroll
        for (int r = 0; r < 4; ++r) {
            const size_t row = grow0 + i * 16 + r;
            const float ar = (float)arow[row];
            _Float16* outp = Cout + row * (size_t)N_DIM + gcol0;
#pragma unroll
            for (int j = 0; j < 4; ++j) {
                float v = (float)acc[i][j][r] * ar * ac4[j];
                outp[j * 16] = (_Float16)v;  // overflow -> inf, matching fp16 cast
            }
        }
    }
}

// ---------------------------------------------------------------------------
extern "C" void kernel_launch(void* const* d_in, const int* in_sizes, int n_in,
                              void* d_out, int out_size, void* d_ws, size_t ws_size,
                              hipStream_t stream) {
    const int* a = (const int*)d_in[0];       // [M,K] int32 (int8 values)
    const int* b = (const int*)d_in[1];       // [N,K] int32 (int8 values)
    const _Float16* ar = (const _Float16*)d_in[2];  // [M] fp16
    const _Float16* ac = (const _Float16*)d_in[3];  // [N] fp16
    _Float16* out = (_Float16*)d_out;         // [M,N] fp16

    unsigned char* pa = (unsigned char*)d_ws;
    unsigned char* pb = pa + (size_t)M_DIM * K_DIM;

    const int pack_blocks = (int)(((size_t)M_DIM * K_DIM + (size_t)N_DIM * K_DIM) / 16 / 256);
    pack_kernel<<<pack_blocks, 256, 0, stream>>>(a, b, pa, pb);

    dim3 grid(N_DIM / 128, M_DIM / 128);
    gemm_i8<<<grid, 256, 0, stream>>>(pa, pb, ar, ac, out);
}

// Round 2
// 393.035 us; speedup vs baseline: 1.0365x; 1.0365x over previous
//
#include <hip/hip_runtime.h>
#include <cstdint>
#include <cstddef>

#define M_DIM 4096
#define N_DIM 8192
#define K_DIM 4096

typedef __attribute__((ext_vector_type(4))) int int4v;

// ---------------------------------------------------------------------------
// Pack: int32 (values 0..126) -> int8, A into pa [M,K], B into pb [N,K].
// Each thread converts 16 ints (4x dwordx4 loads) -> one 16B store.
// ---------------------------------------------------------------------------
__global__ void __launch_bounds__(256) pack_kernel(const int* __restrict__ a,
                                                   const int* __restrict__ b,
                                                   unsigned char* __restrict__ pa,
                                                   unsigned char* __restrict__ pb) {
    size_t t = (size_t)blockIdx.x * 256 + threadIdx.x;
    const size_t NA16 = (size_t)M_DIM * K_DIM / 16;  // A chunks
    const int* __restrict__ src;
    unsigned char* __restrict__ dst;
    if (t < NA16) {
        src = a; dst = pa;
    } else {
        src = b; dst = pb; t -= NA16;
    }
    const int4v* s4 = (const int4v*)src + t * 4;
    int4v o;
#pragma unroll
    for (int q = 0; q < 4; ++q) {
        int4v v = s4[q];
        o[q] = (v[0] & 0xff) | ((v[1] & 0xff) << 8) | ((v[2] & 0xff) << 16) | (v[3] << 24);
    }
    ((int4v*)dst)[t] = o;
}

// ---------------------------------------------------------------------------
// GEMM: C[m][n] = sum_k A[m][k]*B[n][k], int8, i32 accum, scale epilogue.
// 128x128 tile, 256 thr (2x2 waves of 64x64), BK=128 bytes per barrier
// (2 half-K MFMA passes, 32 MFMA/wave/barrier), mfma_i32_16x16x64_i8.
// LDS XOR swizzle: chunk slot = c ^ (row & 7)  (16B chunks, 128B rows)
// -> conflict-free ds_read_b128 fragment reads; applied on the GLOBAL
// address side so global_load_lds staging (uniform base + lane*16) works.
// ---------------------------------------------------------------------------
__device__ inline void async_copy16(const unsigned char* g, unsigned char* l) {
    __builtin_amdgcn_global_load_lds(
        (const __attribute__((address_space(1))) void*)g,
        (__attribute__((address_space(3))) void*)l,
        16, 0, 0);
}

__global__ void __launch_bounds__(256) gemm_i8(const unsigned char* __restrict__ Ap,
                                               const unsigned char* __restrict__ Bp,
                                               const _Float16* __restrict__ arow,
                                               const _Float16* __restrict__ acol,
                                               _Float16* __restrict__ Cout) {
    __shared__ __align__(16) unsigned char As[128 * 128];
    __shared__ __align__(16) unsigned char Bs[128 * 128];

    const int tid  = threadIdx.x;
    const int lane = tid & 63;
    const int wave = tid >> 6;
    const int bn   = blockIdx.x;  // 0..63
    const int bm   = blockIdx.y;  // 0..31

    const int wm = (wave & 1) * 64;   // wave's row offset within 128-tile
    const int wn = (wave >> 1) * 64;  // wave's col offset within 128-tile

    const size_t a_row0 = (size_t)bm * 128;
    const size_t b_row0 = (size_t)bn * 128;

    // --- staging addressing: wave w stages rows [w*32, w*32+32) of each tile
    // in 4 rounds of 8 rows (64 lanes = 8 rows x 8 chunks of 16B).
    // LDS slot for lane l in a round: row = l>>3, chunk c' = l&7 (linear, HW).
    // Global chunk it must hold: c = c' ^ (row & 7) = (l&7) ^ (l>>3).
    const int srow   = lane >> 3;                 // 0..7 within round
    const int schunk = (lane & 7) ^ srow;         // swizzled global chunk
    const unsigned char* ag = Ap + (a_row0 + wave * 32 + srow) * (size_t)K_DIM + schunk * 16;
    const unsigned char* bg = Bp + (b_row0 + wave * 32 + srow) * (size_t)K_DIM + schunk * 16;
    unsigned char* al = As + wave * 4096;  // + round*1024; rows advance 8/round
    unsigned char* bl = Bs + wave * 4096;

    // --- fragment addressing (16x16x64 i8: lane holds 16B of row lane&15,
    // K-chunk lane>>4 within each 64B half). Swizzled chunk offset:
    // half h chunk = h*4 + (lane>>4); slot = chunk ^ (lane&7)  (row&7==lane&7).
    const int fr_x0    = (((lane >> 4) ^ (lane & 7)) << 4);  // h=0 byte offset
    const int a_fr_row = wm + (lane & 15);
    const int b_fr_row = wn + (lane & 15);

    int4v acc[4][4];
#pragma unroll
    for (int i = 0; i < 4; ++i)
#pragma unroll
        for (int j = 0; j < 4; ++j) acc[i][j] = (int4v)0;

    for (int kt = 0; kt < K_DIM; kt += 128) {
#pragma unroll
        for (int r4 = 0; r4 < 4; ++r4) {
            async_copy16(ag + kt + r4 * 8 * K_DIM, al + r4 * 1024);
            async_copy16(bg + kt + r4 * 8 * K_DIM, bl + r4 * 1024);
        }
        __syncthreads();

#pragma unroll
        for (int h = 0; h < 2; ++h) {
            const int off = fr_x0 ^ (h << 6);
            int4v af[4], bf[4];
#pragma unroll
            for (int i = 0; i < 4; ++i)
                af[i] = *(const int4v*)(As + (size_t)(a_fr_row + i * 16) * 128 + off);
#pragma unroll
            for (int j = 0; j < 4; ++j)
                bf[j] = *(const int4v*)(Bs + (size_t)(b_fr_row + j * 16) * 128 + off);

#pragma unroll
            for (int i = 0; i < 4; ++i)
#pragma unroll
                for (int j = 0; j < 4; ++j)
                    acc[i][j] = __builtin_amdgcn_mfma_i32_16x16x64_i8(af[i], bf[j],
                                                                      acc[i][j], 0, 0, 0);
        }
        __syncthreads();
    }

    // --- epilogue: C/D layout col=lane&15, row=(lane>>4)*4+reg
    const int gcol0 = (int)b_row0 + wn + (lane & 15);
    float ac4[4];
#pragma unroll
    for (int j = 0; j < 4; ++j) ac4[j] = (float)acol[gcol0 + j * 16];

    const size_t grow0 = a_row0 + wm + (lane >> 4) * 4;
#pragma unroll
    for (int i = 0; i < 4; ++i) {
#pragma unroll
        for (int r = 0; r < 4; ++r) {
            const size_t row = grow0 + i * 16 + r;
            const float ar = (float)arow[row];
            _Float16* outp = Cout + row * (size_t)N_DIM + gcol0;
#pragma unroll
            for (int j = 0; j < 4; ++j) {
                float v = (float)acc[i][j][r] * ar * ac4[j];
                outp[j * 16] = (_Float16)v;  // overflow -> inf, matching fp16 cast
            }
        }
    }
}

// ---------------------------------------------------------------------------
extern "C" void kernel_launch(void* const* d_in, const int* in_sizes, int n_in,
                              void* d_out, int out_size, void* d_ws, size_t ws_size,
                              hipStream_t stream) {
    const int* a = (const int*)d_in[0];             // [M,K] int32 (int8 values)
    const int* b = (const int*)d_in[1];             // [N,K] int32 (int8 values)
    const _Float16* ar = (const _Float16*)d_in[2];  // [M] fp16
    const _Float16* ac = (const _Float16*)d_in[3];  // [N] fp16
    _Float16* out = (_Float16*)d_out;               // [M,N] fp16

    unsigned char* pa = (unsigned char*)d_ws;
    unsigned char* pb = pa + (size_t)M_DIM * K_DIM;

    const int pack_blocks = (int)(((size_t)M_DIM * K_DIM + (size_t)N_DIM * K_DIM) / 16 / 256);
    pack_kernel<<<pack_blocks, 256, 0, stream>>>(a, b, pa, pb);

    dim3 grid(N_DIM / 128, M_DIM / 128);
    gemm_i8<<<grid, 256, 0, stream>>>(pa, pb, ar, ac, out);
}

// Round 3
// 392.819 us; speedup vs baseline: 1.0370x; 1.0005x over previous
//
#include <hip/hip_runtime.h>
#include <cstdint>
#include <cstddef>

#define M_DIM 4096
#define N_DIM 8192
#define K_DIM 4096

typedef __attribute__((ext_vector_type(4))) int int4v;

// ---------------------------------------------------------------------------
// Pack into MFMA-fragment order (int32 -> int8).
// Layout: 16-row panels; kstep = 64 K-bytes; chunk(p,s) = 1024 B where
// lane l holds row 16p+(l&15), k-bytes s*64 + (l>>4)*16 .. +16.
// Panel stride = 16*K = 65536 B; within panel, ksteps contiguous (1024 B each).
// One thread = one 16B lane-fragment: 4x dwordx4 reads (64B region, every
// byte used), one 16B write (perfectly coalesced: consecutive t -> +16 B).
// ---------------------------------------------------------------------------
__global__ void __launch_bounds__(256) pack_frag(const int* __restrict__ a,
                                                 const int* __restrict__ b,
                                                 unsigned char* __restrict__ pa,
                                                 unsigned char* __restrict__ pb) {
    size_t t = (size_t)blockIdx.x * 256 + threadIdx.x;
    const size_t NA = (size_t)(M_DIM / 16) * (K_DIM / 64) * 64;  // 1,048,576
    const int* __restrict__ src;
    unsigned char* __restrict__ dst;
    if (t < NA) {
        src = a; dst = pa;
    } else {
        src = b; dst = pb; t -= NA;
    }
    const int l = (int)(t & 63);
    const int s = (int)((t >> 6) & 63);
    const int p = (int)(t >> 12);
    const int* g = src + ((size_t)(16 * p + (l & 15))) * K_DIM + s * 64 + (l >> 4) * 16;
    const int4v* g4 = (const int4v*)g;
    int4v o;
#pragma unroll
    for (int q = 0; q < 4; ++q) {
        int4v v = g4[q];
        o[q] = (v[0] & 0xff) | ((v[1] & 0xff) << 8) | ((v[2] & 0xff) << 16) | (v[3] << 24);
    }
    ((int4v*)dst)[t] = o;
}

// ---------------------------------------------------------------------------
// GEMM: 128x128 block, 256 thr (2x2 waves of 64x64), mfma_i32_16x16x64_i8
// (verified layout). A fragments: direct coalesced buffer loads from
// fragment-ordered pa (no LDS). B: 16 KB/tile linear-staged via
// global_load_lds, ds_read_b128 at base+lane*16 (conflict-free, no swizzle).
// ---------------------------------------------------------------------------
__device__ inline void async_copy16(const unsigned char* g, unsigned char* l) {
    __builtin_amdgcn_global_load_lds(
        (const __attribute__((address_space(1))) void*)g,
        (__attribute__((address_space(3))) void*)l,
        16, 0, 0);
}

__global__ void __launch_bounds__(256) gemm_i8(const unsigned char* __restrict__ Ap,
                                               const unsigned char* __restrict__ Bp,
                                               const _Float16* __restrict__ arow,
                                               const _Float16* __restrict__ acol,
                                               _Float16* __restrict__ Cout) {
    __shared__ __align__(16) unsigned char Bs[16384];  // 8 B-panels x 2 ksteps x 1024 B

    const int tid  = threadIdx.x;
    const int lane = tid & 63;
    const int wave = tid >> 6;
    const int bn   = blockIdx.x;  // 0..63
    const int bm   = blockIdx.y;  // 0..31

    const int wm = (wave & 1) * 64;   // wave row offset in 128-tile
    const int wn = (wave >> 1) * 64;  // wave col offset in 128-tile

    // A fragment base: panels bm*8 + wm/16 + i; per tile add gk=T*2048, +h*1024
    const unsigned char* Abase =
        Ap + ((size_t)(bm * 8 + (wm >> 4))) * 65536 + lane * 16;

    // B staging: round r stages LDS [r*4096, r*4096+4096). Uniform part per wave:
    // offu = r*4096 + wave*1024; panel_local = offu>>11; within = offu&2047.
    // Global = Bp + (bn*8+panel_local)*65536 + gk + within + lane*16.
    const size_t Bblk = (size_t)bn * 8 * 65536;
    const unsigned char* bg[4];
    unsigned char* bl[4];
#pragma unroll
    for (int r = 0; r < 4; ++r) {
        const int offu = r * 4096 + wave * 1024;
        bg[r] = Bp + Bblk + (size_t)(offu >> 11) * 65536 + (offu & 2047) + lane * 16;
        bl[r] = Bs + offu;  // wave-uniform; HW adds lane*16
    }

    // B fragment LDS offsets: panel (wn>>4)+j, kstep h
    const int bf_base = ((wn >> 4) << 11) + lane * 16;  // + j*2048 + h*1024

    int4v acc[4][4];
#pragma unroll
    for (int i = 0; i < 4; ++i)
#pragma unroll
        for (int j = 0; j < 4; ++j) acc[i][j] = (int4v)0;

    for (int T = 0; T < K_DIM / 128; ++T) {
        const int gk = T * 2048;  // byte offset within each panel

        // A fragments for both ksteps — plain loads, no barrier coupling
        int4v af[2][4];
#pragma unroll
        for (int h = 0; h < 2; ++h)
#pragma unroll
            for (int i = 0; i < 4; ++i)
                af[h][i] = *(const int4v*)(Abase + (size_t)i * 65536 + gk + h * 1024);

        // stage B tile (16 KB)
#pragma unroll
        for (int r = 0; r < 4; ++r) async_copy16(bg[r] + gk, bl[r]);
        __syncthreads();

#pragma unroll
        for (int h = 0; h < 2; ++h) {
            int4v bf[4];
#pragma unroll
            for (int j = 0; j < 4; ++j)
                bf[j] = *(const int4v*)(Bs + bf_base + j * 2048 + h * 1024);
#pragma unroll
            for (int i = 0; i < 4; ++i)
#pragma unroll
                for (int j = 0; j < 4; ++j)
                    acc[i][j] = __builtin_amdgcn_mfma_i32_16x16x64_i8(af[h][i], bf[j],
                                                                      acc[i][j], 0, 0, 0);
        }
        __syncthreads();
    }

    // --- epilogue: C/D layout col=lane&15, row=(lane>>4)*4+reg (verified)
    const int gcol0 = bn * 128 + wn + (lane & 15);
    float ac4[4];
#pragma unroll
    for (int j = 0; j < 4; ++j) ac4[j] = (float)acol[gcol0 + j * 16];

    const size_t grow0 = (size_t)bm * 128 + wm + (lane >> 4) * 4;
#pragma unroll
    for (int i = 0; i < 4; ++i) {
#pragma unroll
        for (int r = 0; r < 4; ++r) {
            const size_t row = grow0 + i * 16 + r;
            const float ar = (float)arow[row];
            _Float16* outp = Cout + row * (size_t)N_DIM + gcol0;
#pragma unroll
            for (int j = 0; j < 4; ++j) {
                float v = (float)acc[i][j][r] * ar * ac4[j];
                outp[j * 16] = (_Float16)v;
            }
        }
    }
}

// ---------------------------------------------------------------------------
extern "C" void kernel_launch(void* const* d_in, const int* in_sizes, int n_in,
                              void* d_out, int out_size, void* d_ws, size_t ws_size,
                              hipStream_t stream) {
    const int* a = (const int*)d_in[0];             // [M,K] int32 (int8 values)
    const int* b = (const int*)d_in[1];             // [N,K] int32 (int8 values)
    const _Float16* ar = (const _Float16*)d_in[2];  // [M] fp16
    const _Float16* ac = (const _Float16*)d_in[3];  // [N] fp16
    _Float16* out = (_Float16*)d_out;               // [M,N] fp16

    unsigned char* pa = (unsigned char*)d_ws;                       // 16 MB
    unsigned char* pb = pa + (size_t)M_DIM * K_DIM;                 // 32 MB

    const size_t total_frag = (size_t)(M_DIM / 16 + N_DIM / 16) * (K_DIM / 64) * 64;
    pack_frag<<<(int)(total_frag / 256), 256, 0, stream>>>(a, b, pa, pb);

    dim3 grid(N_DIM / 128, M_DIM / 128);
    gemm_i8<<<grid, 256, 0, stream>>>(pa, pb, ar, ac, out);
}